// Round 3
// baseline (249.748 us; speedup 1.0000x reference)
//
#include <hip/hip_runtime.h>
#include <hip/hip_bf16.h>

#define DEV static __device__ __forceinline__

typedef short bf16x8 __attribute__((ext_vector_type(8)));
typedef float f32x4  __attribute__((ext_vector_type(4)));
typedef unsigned u32x4 __attribute__((ext_vector_type(4)));

union U4 { uint4 u; bf16x8 s; };

DEV float b2f(__hip_bfloat16 v) { return __bfloat162float(v); }
DEV float lrelu(float e) { return e > 0.f ? e : 0.2f * e; }

DEV unsigned short f2bu(float f) {
    __hip_bfloat16 b = __float2bfloat16(f);
    return *reinterpret_cast<unsigned short*>(&b);
}
DEV float bu2f(unsigned short u) { return __uint_as_float((unsigned)u << 16); }

DEV float loadF(const void* p, size_t i, int f32) {
    if (f32) return ((const float*)p)[i];
    return b2f(((const __hip_bfloat16*)p)[i]);
}

DEV uint4 pack8(const unsigned short* t) {
    uint4 v;
    v.x = (unsigned)t[0] | ((unsigned)t[1] << 16);
    v.y = (unsigned)t[2] | ((unsigned)t[3] << 16);
    v.z = (unsigned)t[4] | ((unsigned)t[5] << 16);
    v.w = (unsigned)t[6] | ((unsigned)t[7] << 16);
    return v;
}

DEV u32x4 pack8v(const unsigned short* t) {
    u32x4 v;
    v.x = (unsigned)t[0] | ((unsigned)t[1] << 16);
    v.y = (unsigned)t[2] | ((unsigned)t[3] << 16);
    v.z = (unsigned)t[4] | ((unsigned)t[5] << 16);
    v.w = (unsigned)t[6] | ((unsigned)t[7] << 16);
    return v;
}

DEV void edge_sd(int i, int E, const int* __restrict__ src, const int* __restrict__ dst,
                 int& s, int& d) {
    if (i < E) { s = src[i]; d = dst[i]; }
    else       { s = d = i - E; }  // self-loops appended as arange(N)
}

// detect helper: wave-level 256-sample scan of one array's low 16-bit halves
DEV int detect_wave(const void* p, int n, int lane) {
    const unsigned short* u16 = (const unsigned short*)p;
    bool insane = false;
#pragma unroll
    for (int r = 0; r < 4; ++r) {
        int idx = lane + r * 64;
        if (idx < n) {
            unsigned short u = u16[idx];
            unsigned e = (u >> 7) & 0xFFu;
            insane |= (e >= 0xC8u) || (e == 0u && (u & 0x7Fu) != 0u);
        }
    }
    return (__ballot(insane) != 0ull) ? 1 : 0;
}

#define G_BIN 128

// ---------------- K1: fused gemm1 (blocks [0,gb)) + binA hist ([gb,gb+G_BIN))
//                  + dtype detect (block gb+G_BIN) ----------------
__global__ __launch_bounds__(256) void k_fused1(
    // gemm1
    const void* __restrict__ x, const void* __restrict__ W,
    const void* __restrict__ a_s, const void* __restrict__ a_d,
    __hip_bfloat16* __restrict__ h, float* __restrict__ als, float* __restrict__ ald,
    int N, int gb, int nx, int nW1,
    // binA
    const int* __restrict__ src, const int* __restrict__ dst,
    int* __restrict__ hist, int E, int EA, int chunk,
    // detect (for downstream kernels)
    const void* a5, int n5, const void* a6, int n6, const void* a7, int n7,
    const void* a8, int n8, const void* a9, int n9,
    int* __restrict__ flags)
{
    const int tid = threadIdx.x;
    const int bid = blockIdx.x;

    if (bid >= gb) {
        if (bid == gb + G_BIN) {
            // global detect for downstream consumers (flags[0..8])
            const void* ps[9] = {x, W, a_s, a_d, a5, a6, a7, a8, a9};
            const int   ns[9] = {nx, nW1, 64, 64, n5, n6, n7, n8, n9};
            const int w = tid >> 6, lane = tid & 63;
            for (int k = w; k < 9; k += 4) {
                int f = detect_wave(ps[k], ns[k], lane);
                if (lane == 0) flags[k] = f;
            }
            return;
        }
        // ---- binA: coarse histogram ----
        __shared__ int cnt[256];
        cnt[tid] = 0;
        __syncthreads();
        const int cb = bid - gb;
        const int lo = cb * chunk;
        const int hi = min(lo + chunk, EA);
        for (int i = lo + tid; i < hi; i += 256) {
            int s, d; edge_sd(i, E, src, dst, s, d);
            atomicAdd(&cnt[d >> 8], 1);
        }
        __syncthreads();
        hist[cb * 256 + tid] = cnt[tid];
        return;
    }

    // ---- gemm1: h = x(N,128)@W1(128,64) + fused logits ----
    __shared__ __align__(16) unsigned short sMem[2 * 64 * 136];
    __shared__ float sAs[64], sAd[64];
    __shared__ int sFl[4];
    unsigned short* sA = sMem;
    unsigned short* sB = sMem + 64 * 136;
    float* sOut = (float*)sMem;

    {   // inline dtype detect: wave w checks array w
        const void* ps4[4] = {x, W, a_s, a_d};
        const int   ns4[4] = {nx, nW1, 64, 64};
        const int w = tid >> 6, lane = tid & 63;
        int f = detect_wave(ps4[w], ns4[w], lane);
        if (lane == 0) sFl[w] = f;
    }
    __syncthreads();
    const int fx = sFl[0], fw = sFl[1];

    const int row0 = bid * 64;
    if (tid < 64) sAs[tid] = loadF(a_s, tid, sFl[2]);
    else if (tid < 128) sAd[tid - 64] = loadF(a_d, tid - 64, sFl[3]);

    if (!fx) {
        const uint4* xg = (const uint4*)x;
#pragma unroll
        for (int it = 0; it < 2; ++it) {
            int g = tid + it * 256;
            int r = g >> 4, c16 = g & 15;
            uint4 v = (row0 + r < N) ? xg[(size_t)(row0 + r) * 16 + c16]
                                     : make_uint4(0, 0, 0, 0);
            *(uint4*)(sA + r * 136 + c16 * 8) = v;
        }
    } else {
        for (int i = tid; i < 64 * 128; i += 256) {
            int r = i >> 7, k = i & 127;
            float v = (row0 + r < N) ? ((const float*)x)[(size_t)(row0 + r) * 128 + k] : 0.f;
            sA[r * 136 + k] = f2bu(v);
        }
    }
    if (!fw) {
        const unsigned short* Wg = (const unsigned short*)W;
        const int n = tid & 63;
        int k0 = (tid >> 6) * 8;
#pragma unroll
        for (int rep = 0; rep < 4; ++rep, k0 += 32) {
            unsigned short t[8];
#pragma unroll
            for (int j = 0; j < 8; ++j) t[j] = Wg[(size_t)(k0 + j) * 64 + n];
            *(uint4*)(sB + n * 136 + k0) = pack8(t);
        }
    } else {
        const float* Wg = (const float*)W;
        for (int i = tid; i < 128 * 64; i += 256) {
            int k = i >> 6, n = i & 63;
            sB[n * 136 + k] = f2bu(Wg[i]);
        }
    }
    __syncthreads();

    const int w = tid >> 6, lane = tid & 63;
    const int m0 = w * 16;
    const int qr = lane >> 4;
    const int lc = lane & 15;

    bf16x8 afrag[4];
#pragma unroll
    for (int c = 0; c < 4; ++c) {
        U4 u; u.u = *(const uint4*)(sA + (m0 + lc) * 136 + c * 32 + qr * 8);
        afrag[c] = u.s;
    }
    f32x4 accs[4];
#pragma unroll
    for (int nt = 0; nt < 4; ++nt) {
        f32x4 acc = {0.f, 0.f, 0.f, 0.f};
#pragma unroll
        for (int c = 0; c < 4; ++c) {
            U4 u; u.u = *(const uint4*)(sB + (nt * 16 + lc) * 136 + c * 32 + qr * 8);
            acc = __builtin_amdgcn_mfma_f32_16x16x32_bf16(afrag[c], u.s, acc, 0, 0, 0);
        }
        accs[nt] = acc;
    }
    __syncthreads();

#pragma unroll
    for (int nt = 0; nt < 4; ++nt)
#pragma unroll
        for (int reg = 0; reg < 4; ++reg)
            sOut[(m0 + qr * 4 + reg) * 68 + nt * 16 + lc] = accs[nt][reg];
    __syncthreads();

    {
        const int r = tid >> 2, seg = tid & 3;
        const int row = row0 + r;
        const float* po = sOut + r * 68 + seg * 16;
        float ps = 0.f, pd = 0.f;
        unsigned short ob[16];
#pragma unroll
        for (int i = 0; i < 16; ++i) {
            float v = po[i];
            ps = fmaf(v, sAs[seg * 16 + i], ps);
            pd = fmaf(v, sAd[seg * 16 + i], pd);
            ob[i] = f2bu(v);
        }
        if (row < N) {
            uint4* hp = (uint4*)((unsigned short*)h + (size_t)row * 64 + seg * 16);
            hp[0] = pack8(ob);
            hp[1] = pack8(ob + 8);
        }
        ps += __shfl_xor(ps, 1, 64); ps += __shfl_xor(ps, 2, 64);
        pd += __shfl_xor(pd, 1, 64); pd += __shfl_xor(pd, 2, 64);
        if (seg == 0 && row < N) { als[row] = ps; ald[row] = pd; }
    }
}

// ---------------- binC2: fused scan + scatter ----------------
__global__ __launch_bounds__(256) void k_binC2(
    const int* __restrict__ src, const int* __restrict__ dst,
    const int* __restrict__ hist, int* __restrict__ btot,
    unsigned* __restrict__ ebuf, int E, int EA, int chunk)
{
    __shared__ int sm[256];
    __shared__ int cur[256];
    const int tid = threadIdx.x;
    const int cb = blockIdx.x;

    int tot = 0, mine = 0;
#pragma unroll 4
    for (int c = 0; c < G_BIN; ++c) {
        int v = hist[c * 256 + tid];     // coalesced across tid
        tot += v;
        if (c < cb) mine += v;
    }
    if (cb == 0) btot[tid] = tot;
    sm[tid] = tot;
    __syncthreads();
#pragma unroll
    for (int off = 1; off < 256; off <<= 1) {
        int t = (tid >= off) ? sm[tid - off] : 0;
        __syncthreads();
        sm[tid] += t;
        __syncthreads();
    }
    cur[tid] = (sm[tid] - tot) + mine;   // bucket start + my block's offset
    __syncthreads();
    const int lo = cb * chunk;
    const int hi = min(lo + chunk, EA);
    for (int i = lo + tid; i < hi; i += 256) {
        int s, d; edge_sd(i, E, src, dst, s, d);
        int pos = atomicAdd(&cur[d >> 8], 1);
        ebuf[pos] = ((unsigned)(d & 255) << 17) | (unsigned)s;
    }
}

// ---------------- binD: per-bucket node sort -> row_ptr + col ----------------
__global__ __launch_bounds__(256) void k_binD(
    const unsigned* __restrict__ ebuf, const int* __restrict__ btot,
    int* __restrict__ row_ptr, int* __restrict__ col, int N)
{
    __shared__ int sm[256];
    __shared__ int cnt[256];
    __shared__ int pfx[256];
    const int tid = threadIdx.x;
    const int b = blockIdx.x;
    {
        int v = btot[tid];
        sm[tid] = v;
        __syncthreads();
#pragma unroll
        for (int off = 1; off < 256; off <<= 1) {
            int t = (tid >= off) ? sm[tid - off] : 0;
            __syncthreads();
            sm[tid] += t;
            __syncthreads();
        }
    }
    const int lo = (b == 0) ? 0 : sm[b - 1];
    const int hi = sm[b];
    cnt[tid] = 0;
    __syncthreads();
    for (int i = lo + tid; i < hi; i += 256)
        atomicAdd(&cnt[ebuf[i] >> 17], 1);
    __syncthreads();
    const int c = cnt[tid];
    pfx[tid] = c;
    __syncthreads();
#pragma unroll
    for (int off = 1; off < 256; off <<= 1) {
        int t = (tid >= off) ? pfx[tid - off] : 0;
        __syncthreads();
        pfx[tid] += t;
        __syncthreads();
    }
    const int excl = pfx[tid] - c;
    const int d = b * 256 + tid;
    if (d <= N) row_ptr[d] = lo + excl;
    __syncthreads();
    cnt[tid] = lo + excl;              // reuse as absolute cursor
    __syncthreads();
    for (int i = lo + tid; i < hi; i += 256) {
        unsigned v = ebuf[i];
        int pos = atomicAdd(&cnt[v >> 17], 1);
        col[pos] = (int)(v & 0x1FFFFu);
    }
}

// ---------------- gather1 + fused layer-2 GEMM ----------------
// Per node: CSR gather/softmax-aggregate (layer 1), then in-wave:
// rel = relu(agg + b1); h2 = rel @ W2 (lane n owns output col n, rel
// broadcast via shfl, W2 staged in LDS f32); als2/ald2 via butterfly.
// Eliminates the separate gemm2 kernel + the agg bf16 round-trip.
__global__ __launch_bounds__(256) void k_gather1(
    const int* __restrict__ row_ptr, const int* __restrict__ col,
    const float* __restrict__ als, const float* __restrict__ ald,
    const __hip_bfloat16* __restrict__ h,
    __hip_bfloat16* __restrict__ h2,
    float* __restrict__ als2, float* __restrict__ ald2,
    const void* __restrict__ b1, const void* __restrict__ W2,
    const void* __restrict__ a_s2, const void* __restrict__ a_d2,
    const int* __restrict__ flags, int N)
{
    __shared__ float sW2[64 * 65];
    __shared__ float sB1[64], sAs2[64], sAd2[64];

    const int tid = threadIdx.x;
    {   // stage W2 (f32, [k][n] stride 65 -> lane-column reads conflict-free)
        const int fw2 = flags[5];
        for (int i = tid; i < 64 * 64; i += 256) {
            int k = i >> 6, n = i & 63;
            sW2[k * 65 + n] = loadF(W2, i, fw2);
        }
        if (tid < 64) sB1[tid] = loadF(b1, tid, flags[4]);
        else if (tid < 128) sAs2[tid - 64] = loadF(a_s2, tid - 64, flags[6]);
        else if (tid < 192) sAd2[tid - 128] = loadF(a_d2, tid - 128, flags[7]);
    }
    __syncthreads();

    const int lane = tid & 63;
    const int eg = lane >> 3, fg = lane & 7;
    const int wid = blockIdx.x * 4 + (tid >> 6);
    const int nw  = gridDim.x * 4;
    const int npw = (N + nw - 1) / nw;
    const int base = wid * npw;
    if (base >= N) return;
    const int cnt = min(npw, N - base);

    const float a2s = sAs2[lane], a2d = sAd2[lane];

    int rp = 0; float aldv = 0.f;
    if (lane <= cnt) rp = row_ptr[base + lane];
    if (lane < cnt)  aldv = ald[base + lane];

    for (int k = 0; k < cnt; ++k) {
        const int d = base + k;
        const int beg = __shfl(rp, k, 64);
        const int end = __shfl(rp, k + 1, 64);
        const float aldd = __shfl(aldv, k, 64);

        float acc[8] = {0.f,0.f,0.f,0.f,0.f,0.f,0.f,0.f};
        float den = 0.f;
        int j = beg + eg;
        if (j < end) {
            int sC = col[j];
            float alsC = als[sC];
            for (; j < end; j += 8) {
                const int jn = j + 8;
                int sN = 0; float alsN = 0.f;
                if (jn < end) { sN = col[jn]; alsN = als[sN]; }   // 1-ahead
                const float w = __expf(lrelu(alsC + aldd));
                const uint4 hv = *reinterpret_cast<const uint4*>(h + (size_t)sC * 64 + fg * 8);
                den += w;
                acc[0] = fmaf(w, __uint_as_float(hv.x << 16),          acc[0]);
                acc[1] = fmaf(w, __uint_as_float(hv.x & 0xFFFF0000u),  acc[1]);
                acc[2] = fmaf(w, __uint_as_float(hv.y << 16),          acc[2]);
                acc[3] = fmaf(w, __uint_as_float(hv.y & 0xFFFF0000u),  acc[3]);
                acc[4] = fmaf(w, __uint_as_float(hv.z << 16),          acc[4]);
                acc[5] = fmaf(w, __uint_as_float(hv.z & 0xFFFF0000u),  acc[5]);
                acc[6] = fmaf(w, __uint_as_float(hv.w << 16),          acc[6]);
                acc[7] = fmaf(w, __uint_as_float(hv.w & 0xFFFF0000u),  acc[7]);
                sC = sN; alsC = alsN;
            }
        }
#pragma unroll
        for (int off = 8; off <= 32; off <<= 1) {
            den += __shfl_xor(den, off, 64);
#pragma unroll
            for (int q = 0; q < 8; ++q) acc[q] += __shfl_xor(acc[q], off, 64);
        }

        // ---- fused layer-2: rel = relu(agg + b1); o = rel @ W2[:,lane] ----
        const float inv = 1.f / den;
        float rel[8];
#pragma unroll
        for (int q = 0; q < 8; ++q) {
            float v = fmaf(acc[q], inv, sB1[fg * 8 + q]);
            rel[q] = v > 0.f ? v : 0.f;
        }
        float o = 0.f;
#pragma unroll
        for (int f = 0; f < 64; ++f) {
            const float rf = __shfl(rel[f & 7], f >> 3, 64);
            o = fmaf(rf, sW2[f * 65 + lane], o);
        }
        // h2 row store: 64 lanes x 2B = coalesced 128B
        h2[(size_t)d * 64 + lane] = *reinterpret_cast<__hip_bfloat16*>(&(unsigned short&)*(unsigned short[]){f2bu(o)});
        // layer-2 logits
        float zs = o * a2s, zd = o * a2d;
#pragma unroll
        for (int off = 1; off <= 32; off <<= 1) {
            zs += __shfl_xor(zs, off, 64);
            zd += __shfl_xor(zd, off, 64);
        }
        if (lane == 0) { als2[d] = zs; ald2[d] = zd; }
    }
}

// ---------------- gather2: CSR gather + softmax + bias -> output ----------------
__global__ __launch_bounds__(256) void k_gather2(
    const int* __restrict__ row_ptr, const int* __restrict__ col,
    const float* __restrict__ als, const float* __restrict__ ald,
    const __hip_bfloat16* __restrict__ h,
    void* __restrict__ final_out,
    const void* __restrict__ bias, const int* __restrict__ flags, int N)
{
    const int tid = threadIdx.x;
    const int lane = tid & 63;
    const int eg = lane >> 3, fg = lane & 7;
    const int wid = blockIdx.x * 4 + (tid >> 6);
    const int nw  = gridDim.x * 4;
    const int npw = (N + nw - 1) / nw;
    const int base = wid * npw;
    if (base >= N) return;
    const int cnt = min(npw, N - base);

    int rp = 0; float aldv = 0.f;
    if (lane <= cnt) rp = row_ptr[base + lane];
    if (lane < cnt)  aldv = ald[base + lane];

    for (int k = 0; k < cnt; ++k) {
        const int d = base + k;
        const int beg = __shfl(rp, k, 64);
        const int end = __shfl(rp, k + 1, 64);
        const float aldd = __shfl(aldv, k, 64);

        float acc[8] = {0.f,0.f,0.f,0.f,0.f,0.f,0.f,0.f};
        float den = 0.f;
        int j = beg + eg;
        if (j < end) {
            int sC = col[j];
            float alsC = als[sC];
            for (; j < end; j += 8) {
                const int jn = j + 8;
                int sN = 0; float alsN = 0.f;
                if (jn < end) { sN = col[jn]; alsN = als[sN]; }   // 1-ahead
                const float w = __expf(lrelu(alsC + aldd));
                const uint4 hv = *reinterpret_cast<const uint4*>(h + (size_t)sC * 64 + fg * 8);
                den += w;
                acc[0] = fmaf(w, __uint_as_float(hv.x << 16),          acc[0]);
                acc[1] = fmaf(w, __uint_as_float(hv.x & 0xFFFF0000u),  acc[1]);
                acc[2] = fmaf(w, __uint_as_float(hv.y << 16),          acc[2]);
                acc[3] = fmaf(w, __uint_as_float(hv.y & 0xFFFF0000u),  acc[3]);
                acc[4] = fmaf(w, __uint_as_float(hv.z << 16),          acc[4]);
                acc[5] = fmaf(w, __uint_as_float(hv.z & 0xFFFF0000u),  acc[5]);
                acc[6] = fmaf(w, __uint_as_float(hv.w << 16),          acc[6]);
                acc[7] = fmaf(w, __uint_as_float(hv.w & 0xFFFF0000u),  acc[7]);
                sC = sN; alsC = alsN;
            }
        }
#pragma unroll
        for (int off = 8; off <= 32; off <<= 1) {
            den += __shfl_xor(den, off, 64);
#pragma unroll
            for (int q = 0; q < 8; ++q) acc[q] += __shfl_xor(acc[q], off, 64);
        }
        if (eg == 0) {
            const float inv = 1.f / den;
            float vb[8];
#pragma unroll
            for (int q = 0; q < 8; ++q) vb[q] = acc[q] * inv + loadF(bias, fg * 8 + q, flags[8]);
            if (flags[0]) {
                float* o = (float*)final_out + (size_t)d * 64 + fg * 8;
                f32x4 o0 = {vb[0], vb[1], vb[2], vb[3]};
                f32x4 o1 = {vb[4], vb[5], vb[6], vb[7]};
                __builtin_nontemporal_store(o0, (f32x4*)o);
                __builtin_nontemporal_store(o1, (f32x4*)(o + 4));
            } else {
                unsigned short ob[8];
#pragma unroll
                for (int q = 0; q < 8; ++q) ob[q] = f2bu(vb[q]);
                __builtin_nontemporal_store(pack8v(ob),
                    reinterpret_cast<u32x4*>((__hip_bfloat16*)final_out + (size_t)d * 64 + fg * 8));
            }
        }
    }
}

extern "C" void kernel_launch(void* const* d_in, const int* in_sizes, int n_in,
                              void* d_out, int out_size, void* d_ws, size_t ws_size,
                              hipStream_t stream)
{
    const void* x   = d_in[0];
    const int*  ei  = (const int*)d_in[1];
    const void* W1  = d_in[2];
    const void* as1 = d_in[3];
    const void* ad1 = d_in[4];
    const void* b1  = d_in[5];
    const void* W2  = d_in[6];
    const void* as2 = d_in[7];
    const void* ad2 = d_in[8];
    const void* b2  = d_in[9];

    const int N  = in_sizes[0] / 128;   // 50000
    const int E  = in_sizes[1] / 2;     // 800000
    const int EA = E + N;
    const int* src = ei;
    const int* dst = ei + E;

    uintptr_t base = (uintptr_t)d_ws;
    auto alloc = [&](size_t bytes) { uintptr_t p = base; base += (bytes + 63) & ~(size_t)63; return p; };
    int*      flags    = (int*)alloc(64 * 4);
    float*    als      = (float*)alloc((size_t)N * 4);
    float*    ald      = (float*)alloc((size_t)N * 4);
    float*    als2     = (float*)alloc((size_t)N * 4);
    float*    ald2     = (float*)alloc((size_t)N * 4);
    int*      row_ptr  = (int*)alloc((size_t)(N + 1) * 4);
    int*      hist     = (int*)alloc((size_t)G_BIN * 256 * 4);
    int*      btot     = (int*)alloc(256 * 4);
    unsigned* ebuf     = (unsigned*)alloc((size_t)EA * 4);
    int*      col      = (int*)alloc((size_t)EA * 4);
    __hip_bfloat16* hbuf   = (__hip_bfloat16*)alloc((size_t)N * 64 * 2);
    __hip_bfloat16* aggbuf = (__hip_bfloat16*)alloc((size_t)N * 64 * 2);

    const int gatherb = 1792;             // 7168 waves * 7 nodes = 50176 >= N
    const int gb  = (N + 63) / 64;        // gemm blocks: 64 rows/block
    const int NBK = (N + 255) / 256;      // dst buckets (<= 256)
    const int chunk = (EA + G_BIN - 1) / G_BIN;

    // ---- K1: gemm1 || binA || detect (all independent) ----
    k_fused1<<<gb + G_BIN + 1, 256, 0, stream>>>(
        x, W1, as1, ad1, hbuf, als, ald, N, gb, in_sizes[0], in_sizes[2],
        src, dst, hist, E, EA, chunk,
        b1, in_sizes[5], W2, in_sizes[6], as2, in_sizes[7], ad2, in_sizes[8],
        b2, in_sizes[9], flags);
    // ---- CSR finish ----
    k_binC2<<<G_BIN, 256, 0, stream>>>(src, dst, hist, btot, ebuf, E, EA, chunk);
    k_binD<<<NBK, 256, 0, stream>>>(ebuf, btot, row_ptr, col, N);

    // ---- layer 1 gather + fused layer-2 GEMM ----
    k_gather1<<<gatherb, 256, 0, stream>>>(row_ptr, col, als, ald, hbuf, aggbuf,
                                           als2, ald2, b1, W2, as2, ad2, flags, N);
    // ---- layer 2 gather -> output ----
    k_gather2<<<gatherb, 256, 0, stream>>>(row_ptr, col, als2, ald2, aggbuf,
                                           d_out, b2, flags, N);
    (void)out_size; (void)ws_size; (void)n_in;
}

// Round 4
// 242.681 us; speedup vs baseline: 1.0291x; 1.0291x over previous
//
#include <hip/hip_runtime.h>
#include <hip/hip_bf16.h>

#define DEV static __device__ __forceinline__

typedef short bf16x8 __attribute__((ext_vector_type(8)));
typedef float f32x4  __attribute__((ext_vector_type(4)));
typedef unsigned u32x4 __attribute__((ext_vector_type(4)));

union U4 { uint4 u; bf16x8 s; };

DEV float b2f(__hip_bfloat16 v) { return __bfloat162float(v); }
DEV float lrelu(float e) { return e > 0.f ? e : 0.2f * e; }

DEV unsigned short f2bu(float f) {
    __hip_bfloat16 b = __float2bfloat16(f);
    return *reinterpret_cast<unsigned short*>(&b);
}
DEV float bu2f(unsigned short u) { return __uint_as_float((unsigned)u << 16); }

DEV float loadF(const void* p, size_t i, int f32) {
    if (f32) return ((const float*)p)[i];
    return b2f(((const __hip_bfloat16*)p)[i]);
}

DEV uint4 pack8(const unsigned short* t) {
    uint4 v;
    v.x = (unsigned)t[0] | ((unsigned)t[1] << 16);
    v.y = (unsigned)t[2] | ((unsigned)t[3] << 16);
    v.z = (unsigned)t[4] | ((unsigned)t[5] << 16);
    v.w = (unsigned)t[6] | ((unsigned)t[7] << 16);
    return v;
}

DEV void edge_sd(int i, int E, const int* __restrict__ src, const int* __restrict__ dst,
                 int& s, int& d) {
    if (i < E) { s = src[i]; d = dst[i]; }
    else       { s = d = i - E; }  // self-loops appended as arange(N)
}

// detect helper: wave-level 256-sample scan of one array's low 16-bit halves
DEV int detect_wave(const void* p, int n, int lane) {
    const unsigned short* u16 = (const unsigned short*)p;
    bool insane = false;
#pragma unroll
    for (int r = 0; r < 4; ++r) {
        int idx = lane + r * 64;
        if (idx < n) {
            unsigned short u = u16[idx];
            unsigned e = (u >> 7) & 0xFFu;
            insane |= (e >= 0xC8u) || (e == 0u && (u & 0x7Fu) != 0u);
        }
    }
    return (__ballot(insane) != 0ull) ? 1 : 0;
}

#define G_BIN 128

// ---------------- K1: fused gemm1 (blocks [0,gb)) + binA hist ([gb,gb+G_BIN))
//                  + dtype detect (block gb+G_BIN) ----------------
__global__ __launch_bounds__(256) void k_fused1(
    // gemm1
    const void* __restrict__ x, const void* __restrict__ W,
    const void* __restrict__ a_s, const void* __restrict__ a_d,
    __hip_bfloat16* __restrict__ h, float* __restrict__ als, float* __restrict__ ald,
    int N, int gb, int nx, int nW1,
    // binA
    const int* __restrict__ src, const int* __restrict__ dst,
    int* __restrict__ hist, int E, int EA, int chunk,
    // detect (for downstream kernels)
    const void* a5, int n5, const void* a6, int n6, const void* a7, int n7,
    const void* a8, int n8, const void* a9, int n9,
    int* __restrict__ flags)
{
    const int tid = threadIdx.x;
    const int bid = blockIdx.x;

    if (bid >= gb) {
        if (bid == gb + G_BIN) {
            // global detect for downstream consumers (flags[0..8])
            const void* ps[9] = {x, W, a_s, a_d, a5, a6, a7, a8, a9};
            const int   ns[9] = {nx, nW1, 64, 64, n5, n6, n7, n8, n9};
            const int w = tid >> 6, lane = tid & 63;
            for (int k = w; k < 9; k += 4) {
                int f = detect_wave(ps[k], ns[k], lane);
                if (lane == 0) flags[k] = f;
            }
            return;
        }
        // ---- binA: coarse histogram ----
        __shared__ int cnt[256];
        cnt[tid] = 0;
        __syncthreads();
        const int cb = bid - gb;
        const int lo = cb * chunk;
        const int hi = min(lo + chunk, EA);
        for (int i = lo + tid; i < hi; i += 256) {
            int s, d; edge_sd(i, E, src, dst, s, d);
            atomicAdd(&cnt[d >> 8], 1);
        }
        __syncthreads();
        hist[cb * 256 + tid] = cnt[tid];
        return;
    }

    // ---- gemm1: h = x(N,128)@W1(128,64) + fused logits ----
    __shared__ __align__(16) unsigned short sMem[2 * 64 * 136];
    __shared__ float sAs[64], sAd[64];
    __shared__ int sFl[4];
    unsigned short* sA = sMem;
    unsigned short* sB = sMem + 64 * 136;
    float* sOut = (float*)sMem;

    {   // inline dtype detect: wave w checks array w
        const void* ps4[4] = {x, W, a_s, a_d};
        const int   ns4[4] = {nx, nW1, 64, 64};
        const int w = tid >> 6, lane = tid & 63;
        int f = detect_wave(ps4[w], ns4[w], lane);
        if (lane == 0) sFl[w] = f;
    }
    __syncthreads();
    const int fx = sFl[0], fw = sFl[1];

    const int row0 = bid * 64;
    if (tid < 64) sAs[tid] = loadF(a_s, tid, sFl[2]);
    else if (tid < 128) sAd[tid - 64] = loadF(a_d, tid - 64, sFl[3]);

    if (!fx) {
        const uint4* xg = (const uint4*)x;
#pragma unroll
        for (int it = 0; it < 2; ++it) {
            int g = tid + it * 256;
            int r = g >> 4, c16 = g & 15;
            uint4 v = (row0 + r < N) ? xg[(size_t)(row0 + r) * 16 + c16]
                                     : make_uint4(0, 0, 0, 0);
            *(uint4*)(sA + r * 136 + c16 * 8) = v;
        }
    } else {
        for (int i = tid; i < 64 * 128; i += 256) {
            int r = i >> 7, k = i & 127;
            float v = (row0 + r < N) ? ((const float*)x)[(size_t)(row0 + r) * 128 + k] : 0.f;
            sA[r * 136 + k] = f2bu(v);
        }
    }
    if (!fw) {
        const unsigned short* Wg = (const unsigned short*)W;
        const int n = tid & 63;
        int k0 = (tid >> 6) * 8;
#pragma unroll
        for (int rep = 0; rep < 4; ++rep, k0 += 32) {
            unsigned short t[8];
#pragma unroll
            for (int j = 0; j < 8; ++j) t[j] = Wg[(size_t)(k0 + j) * 64 + n];
            *(uint4*)(sB + n * 136 + k0) = pack8(t);
        }
    } else {
        const float* Wg = (const float*)W;
        for (int i = tid; i < 128 * 64; i += 256) {
            int k = i >> 6, n = i & 63;
            sB[n * 136 + k] = f2bu(Wg[i]);
        }
    }
    __syncthreads();

    const int w = tid >> 6, lane = tid & 63;
    const int m0 = w * 16;
    const int qr = lane >> 4;
    const int lc = lane & 15;

    bf16x8 afrag[4];
#pragma unroll
    for (int c = 0; c < 4; ++c) {
        U4 u; u.u = *(const uint4*)(sA + (m0 + lc) * 136 + c * 32 + qr * 8);
        afrag[c] = u.s;
    }
    f32x4 accs[4];
#pragma unroll
    for (int nt = 0; nt < 4; ++nt) {
        f32x4 acc = {0.f, 0.f, 0.f, 0.f};
#pragma unroll
        for (int c = 0; c < 4; ++c) {
            U4 u; u.u = *(const uint4*)(sB + (nt * 16 + lc) * 136 + c * 32 + qr * 8);
            acc = __builtin_amdgcn_mfma_f32_16x16x32_bf16(afrag[c], u.s, acc, 0, 0, 0);
        }
        accs[nt] = acc;
    }
    __syncthreads();

#pragma unroll
    for (int nt = 0; nt < 4; ++nt)
#pragma unroll
        for (int reg = 0; reg < 4; ++reg)
            sOut[(m0 + qr * 4 + reg) * 68 + nt * 16 + lc] = accs[nt][reg];
    __syncthreads();

    {
        const int r = tid >> 2, seg = tid & 3;
        const int row = row0 + r;
        const float* po = sOut + r * 68 + seg * 16;
        float ps = 0.f, pd = 0.f;
        unsigned short ob[16];
#pragma unroll
        for (int i = 0; i < 16; ++i) {
            float v = po[i];
            ps = fmaf(v, sAs[seg * 16 + i], ps);
            pd = fmaf(v, sAd[seg * 16 + i], pd);
            ob[i] = f2bu(v);
        }
        if (row < N) {
            uint4* hp = (uint4*)((unsigned short*)h + (size_t)row * 64 + seg * 16);
            hp[0] = pack8(ob);
            hp[1] = pack8(ob + 8);
        }
        ps += __shfl_xor(ps, 1, 64); ps += __shfl_xor(ps, 2, 64);
        pd += __shfl_xor(pd, 1, 64); pd += __shfl_xor(pd, 2, 64);
        if (seg == 0 && row < N) { als[row] = ps; ald[row] = pd; }
    }
}

// ---------------- binC2: fused scan + scatter ----------------
__global__ __launch_bounds__(256) void k_binC2(
    const int* __restrict__ src, const int* __restrict__ dst,
    const int* __restrict__ hist, int* __restrict__ btot,
    unsigned* __restrict__ ebuf, int E, int EA, int chunk)
{
    __shared__ int sm[256];
    __shared__ int cur[256];
    const int tid = threadIdx.x;
    const int cb = blockIdx.x;

    int tot = 0, mine = 0;
#pragma unroll 4
    for (int c = 0; c < G_BIN; ++c) {
        int v = hist[c * 256 + tid];     // coalesced across tid
        tot += v;
        if (c < cb) mine += v;
    }
    if (cb == 0) btot[tid] = tot;
    sm[tid] = tot;
    __syncthreads();
#pragma unroll
    for (int off = 1; off < 256; off <<= 1) {
        int t = (tid >= off) ? sm[tid - off] : 0;
        __syncthreads();
        sm[tid] += t;
        __syncthreads();
    }
    cur[tid] = (sm[tid] - tot) + mine;   // bucket start + my block's offset
    __syncthreads();
    const int lo = cb * chunk;
    const int hi = min(lo + chunk, EA);
    for (int i = lo + tid; i < hi; i += 256) {
        int s, d; edge_sd(i, E, src, dst, s, d);
        int pos = atomicAdd(&cur[d >> 8], 1);
        ebuf[pos] = ((unsigned)(d & 255) << 17) | (unsigned)s;
    }
}

// ---------------- binD: per-bucket node sort -> row_ptr + col ----------------
__global__ __launch_bounds__(256) void k_binD(
    const unsigned* __restrict__ ebuf, const int* __restrict__ btot,
    int* __restrict__ row_ptr, int* __restrict__ col, int N)
{
    __shared__ int sm[256];
    __shared__ int cnt[256];
    __shared__ int pfx[256];
    const int tid = threadIdx.x;
    const int b = blockIdx.x;
    {
        int v = btot[tid];
        sm[tid] = v;
        __syncthreads();
#pragma unroll
        for (int off = 1; off < 256; off <<= 1) {
            int t = (tid >= off) ? sm[tid - off] : 0;
            __syncthreads();
            sm[tid] += t;
            __syncthreads();
        }
    }
    const int lo = (b == 0) ? 0 : sm[b - 1];
    const int hi = sm[b];
    cnt[tid] = 0;
    __syncthreads();
    for (int i = lo + tid; i < hi; i += 256)
        atomicAdd(&cnt[ebuf[i] >> 17], 1);
    __syncthreads();
    const int c = cnt[tid];
    pfx[tid] = c;
    __syncthreads();
#pragma unroll
    for (int off = 1; off < 256; off <<= 1) {
        int t = (tid >= off) ? pfx[tid - off] : 0;
        __syncthreads();
        pfx[tid] += t;
        __syncthreads();
    }
    const int excl = pfx[tid] - c;
    const int d = b * 256 + tid;
    if (d <= N) row_ptr[d] = lo + excl;
    __syncthreads();
    cnt[tid] = lo + excl;              // reuse as absolute cursor
    __syncthreads();
    for (int i = lo + tid; i < hi; i += 256) {
        unsigned v = ebuf[i];
        int pos = atomicAdd(&cnt[v >> 17], 1);
        col[pos] = (int)(v & 0x1FFFFu);
    }
}

// ---------------- MFMA layer-2 GEMM: h2 = relu(agg+b1)@W2(64,64), in-place ----------------
__global__ __launch_bounds__(256) void k_gemm2(
    __hip_bfloat16* __restrict__ agg, const void* __restrict__ b1,
    const void* __restrict__ W, const void* __restrict__ a_s,
    const void* __restrict__ a_d, const int* __restrict__ flags,
    float* __restrict__ als, float* __restrict__ ald, int N)
{
    __shared__ __align__(16) unsigned short sMem[2 * 64 * 72];
    __shared__ float sAs[64], sAd[64], sBias[64];
    unsigned short* sA = sMem;
    unsigned short* sB = sMem + 64 * 72;
    float* sOut = (float*)sMem;

    const int tid = threadIdx.x;
    const int row0 = blockIdx.x * 64;
    const int fw = flags[5];

    if (tid < 64) sAs[tid] = loadF(a_s, tid, flags[6]);
    else if (tid < 128) sAd[tid - 64] = loadF(a_d, tid - 64, flags[7]);
    else if (tid < 192) sBias[tid - 128] = loadF(b1, tid - 128, flags[4]);
    __syncthreads();

    {
        const uint4* ag = (const uint4*)agg;
#pragma unroll
        for (int it = 0; it < 2; ++it) {
            int g = tid + it * 256;
            int r = g >> 3, c8 = g & 7;
            uint4 v = (row0 + r < N) ? ag[(size_t)(row0 + r) * 8 + c8]
                                     : make_uint4(0, 0, 0, 0);
            unsigned short in[8] = {
                (unsigned short)(v.x & 0xFFFF), (unsigned short)(v.x >> 16),
                (unsigned short)(v.y & 0xFFFF), (unsigned short)(v.y >> 16),
                (unsigned short)(v.z & 0xFFFF), (unsigned short)(v.z >> 16),
                (unsigned short)(v.w & 0xFFFF), (unsigned short)(v.w >> 16)};
            unsigned short ob[8];
#pragma unroll
            for (int j = 0; j < 8; ++j) {
                float t = bu2f(in[j]) + sBias[c8 * 8 + j];
                ob[j] = f2bu(t > 0.f ? t : 0.f);
            }
            *(uint4*)(sA + r * 72 + c8 * 8) = pack8(ob);
        }
    }
    if (!fw) {
        const unsigned short* Wg = (const unsigned short*)W;
        const int n = tid & 63;
        int k0 = (tid >> 6) * 8;
#pragma unroll
        for (int rep = 0; rep < 2; ++rep, k0 += 32) {
            unsigned short t[8];
#pragma unroll
            for (int j = 0; j < 8; ++j) t[j] = Wg[(size_t)(k0 + j) * 64 + n];
            *(uint4*)(sB + n * 72 + k0) = pack8(t);
        }
    } else {
        const float* Wg = (const float*)W;
        for (int i = tid; i < 64 * 64; i += 256) {
            int k = i >> 6, n = i & 63;
            sB[n * 72 + k] = f2bu(Wg[i]);
        }
    }
    __syncthreads();

    const int w = tid >> 6, lane = tid & 63;
    const int m0 = w * 16;
    const int qr = lane >> 4, lc = lane & 15;

    bf16x8 afrag[2];
#pragma unroll
    for (int c = 0; c < 2; ++c) {
        U4 u; u.u = *(const uint4*)(sA + (m0 + lc) * 72 + c * 32 + qr * 8);
        afrag[c] = u.s;
    }
    f32x4 accs[4];
#pragma unroll
    for (int nt = 0; nt < 4; ++nt) {
        f32x4 acc = {0.f, 0.f, 0.f, 0.f};
#pragma unroll
        for (int c = 0; c < 2; ++c) {
            U4 u; u.u = *(const uint4*)(sB + (nt * 16 + lc) * 72 + c * 32 + qr * 8);
            acc = __builtin_amdgcn_mfma_f32_16x16x32_bf16(afrag[c], u.s, acc, 0, 0, 0);
        }
        accs[nt] = acc;
    }
    __syncthreads();
#pragma unroll
    for (int nt = 0; nt < 4; ++nt)
#pragma unroll
        for (int reg = 0; reg < 4; ++reg)
            sOut[(m0 + qr * 4 + reg) * 68 + nt * 16 + lc] = accs[nt][reg];
    __syncthreads();

    {
        const int r = tid >> 2, seg = tid & 3;
        const int row = row0 + r;
        const float* po = sOut + r * 68 + seg * 16;
        float ps = 0.f, pd = 0.f;
        unsigned short ob[16];
#pragma unroll
        for (int i = 0; i < 16; ++i) {
            float v = po[i];
            ps = fmaf(v, sAs[seg * 16 + i], ps);
            pd = fmaf(v, sAd[seg * 16 + i], pd);
            ob[i] = f2bu(v);
        }
        if (row < N) {
            uint4* hp = (uint4*)((unsigned short*)agg + (size_t)row * 64 + seg * 16);
            hp[0] = pack8(ob);
            hp[1] = pack8(ob + 8);
        }
        ps += __shfl_xor(ps, 1, 64); ps += __shfl_xor(ps, 2, 64);
        pd += __shfl_xor(pd, 1, 64); pd += __shfl_xor(pd, 2, 64);
        if (seg == 0 && row < N) { als[row] = ps; ald[row] = pd; }
    }
}

// ---------------- CSR gather, lane-per-edge / lane-per-feature ----------------
// Stage 1 (lane = edge): one coalesced col read + up to 64 INDEPENDENT als
// loads in flight; w = exp(lrelu(.)) per lane; den via butterfly.
// Stage 2 (lane = feature): edges consumed in chunks of 8, fully unrolled:
// 8 independent coalesced 128B h-row loads in flight per chunk. This is the
// MLP fix for the latency-bound profile (R3: HBM 6%, VALU 26%, occ 35%).
__global__ __launch_bounds__(256) void k_gather(
    const int* __restrict__ row_ptr, const int* __restrict__ col,
    const float* __restrict__ als, const float* __restrict__ ald,
    const __hip_bfloat16* __restrict__ h,
    __hip_bfloat16* __restrict__ agg_out,
    void* __restrict__ final_out,
    const void* __restrict__ bias, const int* __restrict__ flags, int N)
{
    const int tid = threadIdx.x;
    const int lane = tid & 63;
    const int wid = blockIdx.x * 4 + (tid >> 6);
    const int nw  = gridDim.x * 4;
    const unsigned short* hp = (const unsigned short*)h;

    float bval = 0.f; int f0 = 0;
    if (final_out) { bval = loadF(bias, lane, flags[8]); f0 = flags[0]; }

    for (int d = wid; d < N; d += nw) {
        const int beg = row_ptr[d], end = row_ptr[d + 1];
        const float aldd = ald[d];

        float den = 0.f;
        float a0 = 0.f, a1 = 0.f, a2 = 0.f, a3 = 0.f;
        float a4 = 0.f, a5 = 0.f, a6 = 0.f, a7 = 0.f;

        for (int jb = beg; jb < end; jb += 64) {
            const int m = min(64, end - jb);
            int s = 0; float w = 0.f;
            if (lane < m) {
                s = col[jb + lane];
                w = __expf(lrelu(als[s] + aldd));
            }
            float wsum = w;
#pragma unroll
            for (int off = 1; off <= 32; off <<= 1) wsum += __shfl_xor(wsum, off, 64);
            den += wsum;

            for (int j = 0; j < m; j += 8) {
                float wv[8]; int sv[8]; unsigned short hv[8];
#pragma unroll
                for (int q = 0; q < 8; ++q) {
                    const bool ok = (j + q) < m;          // uniform branch
                    wv[q] = ok ? __shfl(w, j + q, 64) : 0.f;
                    sv[q] = ok ? __shfl(s, j + q, 64) : 0;
                }
#pragma unroll
                for (int q = 0; q < 8; ++q)
                    hv[q] = hp[(size_t)sv[q] * 64 + lane];  // 8 loads in flight
                a0 = fmaf(wv[0], bu2f(hv[0]), a0);
                a1 = fmaf(wv[1], bu2f(hv[1]), a1);
                a2 = fmaf(wv[2], bu2f(hv[2]), a2);
                a3 = fmaf(wv[3], bu2f(hv[3]), a3);
                a4 = fmaf(wv[4], bu2f(hv[4]), a4);
                a5 = fmaf(wv[5], bu2f(hv[5]), a5);
                a6 = fmaf(wv[6], bu2f(hv[6]), a6);
                a7 = fmaf(wv[7], bu2f(hv[7]), a7);
            }
        }
        const float acc = ((a0 + a1) + (a2 + a3)) + ((a4 + a5) + (a6 + a7));
        const float inv = 1.f / den;
        if (final_out) {
            const float vb = fmaf(acc, inv, bval);
            if (f0) ((float*)final_out)[(size_t)d * 64 + lane] = vb;
            else ((unsigned short*)final_out)[(size_t)d * 64 + lane] = f2bu(vb);
        } else {
            ((unsigned short*)agg_out)[(size_t)d * 64 + lane] = f2bu(acc * inv);
        }
    }
}

extern "C" void kernel_launch(void* const* d_in, const int* in_sizes, int n_in,
                              void* d_out, int out_size, void* d_ws, size_t ws_size,
                              hipStream_t stream)
{
    const void* x   = d_in[0];
    const int*  ei  = (const int*)d_in[1];
    const void* W1  = d_in[2];
    const void* as1 = d_in[3];
    const void* ad1 = d_in[4];
    const void* b1  = d_in[5];
    const void* W2  = d_in[6];
    const void* as2 = d_in[7];
    const void* ad2 = d_in[8];
    const void* b2  = d_in[9];

    const int N  = in_sizes[0] / 128;   // 50000
    const int E  = in_sizes[1] / 2;     // 800000
    const int EA = E + N;
    const int* src = ei;
    const int* dst = ei + E;

    uintptr_t base = (uintptr_t)d_ws;
    auto alloc = [&](size_t bytes) { uintptr_t p = base; base += (bytes + 63) & ~(size_t)63; return p; };
    int*      flags    = (int*)alloc(64 * 4);
    float*    als      = (float*)alloc((size_t)N * 4);
    float*    ald      = (float*)alloc((size_t)N * 4);
    int*      row_ptr  = (int*)alloc((size_t)(N + 1) * 4);
    int*      hist     = (int*)alloc((size_t)G_BIN * 256 * 4);
    int*      btot     = (int*)alloc(256 * 4);
    unsigned* ebuf     = (unsigned*)alloc((size_t)EA * 4);
    int*      col      = (int*)alloc((size_t)EA * 4);
    __hip_bfloat16* hbuf   = (__hip_bfloat16*)alloc((size_t)N * 64 * 2);
    __hip_bfloat16* aggbuf = (__hip_bfloat16*)alloc((size_t)N * 64 * 2);

    const int gatherb = 2048;             // 8192 waves, ~6 strided nodes each
    const int gb  = (N + 63) / 64;        // gemm blocks: 64 rows/block
    const int NBK = (N + 255) / 256;      // dst buckets (<= 256)
    const int chunk = (EA + G_BIN - 1) / G_BIN;

    // ---- K1: gemm1 || binA || detect (all independent) ----
    k_fused1<<<gb + G_BIN + 1, 256, 0, stream>>>(
        x, W1, as1, ad1, hbuf, als, ald, N, gb, in_sizes[0], in_sizes[2],
        src, dst, hist, E, EA, chunk,
        b1, in_sizes[5], W2, in_sizes[6], as2, in_sizes[7], ad2, in_sizes[8],
        b2, in_sizes[9], flags);
    // ---- CSR finish ----
    k_binC2<<<G_BIN, 256, 0, stream>>>(src, dst, hist, btot, ebuf, E, EA, chunk);
    k_binD<<<NBK, 256, 0, stream>>>(ebuf, btot, row_ptr, col, N);

    // ---- layer 1 gather ----
    k_gather<<<gatherb, 256, 0, stream>>>(row_ptr, col, als, ald, hbuf, aggbuf,
                                          nullptr, nullptr, flags, N);
    // ---- layer 2 ----
    k_gemm2<<<gb, 256, 0, stream>>>(aggbuf, b1, W2, as2, ad2, flags, als, ald, N);
    k_gather<<<gatherb, 256, 0, stream>>>(row_ptr, col, als, ald, aggbuf, nullptr,
                                          d_out, b2, flags, N);
    (void)out_size; (void)ws_size; (void)n_in;
}

// Round 5
// 200.795 us; speedup vs baseline: 1.2438x; 1.2086x over previous
//
#include <hip/hip_runtime.h>
#include <hip/hip_bf16.h>

#define DEV static __device__ __forceinline__

typedef short bf16x8 __attribute__((ext_vector_type(8)));
typedef float f32x4  __attribute__((ext_vector_type(4)));
typedef unsigned u32x4 __attribute__((ext_vector_type(4)));

union U4 { uint4 u; bf16x8 s; };

DEV float b2f(__hip_bfloat16 v) { return __bfloat162float(v); }
DEV float lrelu(float e) { return e > 0.f ? e : 0.2f * e; }

DEV unsigned short f2bu(float f) {
    __hip_bfloat16 b = __float2bfloat16(f);
    return *reinterpret_cast<unsigned short*>(&b);
}
DEV float bu2f(unsigned short u) { return __uint_as_float((unsigned)u << 16); }

DEV float loadF(const void* p, size_t i, int f32) {
    if (f32) return ((const float*)p)[i];
    return b2f(((const __hip_bfloat16*)p)[i]);
}

DEV uint4 pack8(const unsigned short* t) {
    uint4 v;
    v.x = (unsigned)t[0] | ((unsigned)t[1] << 16);
    v.y = (unsigned)t[2] | ((unsigned)t[3] << 16);
    v.z = (unsigned)t[4] | ((unsigned)t[5] << 16);
    v.w = (unsigned)t[6] | ((unsigned)t[7] << 16);
    return v;
}

DEV u32x4 pack8v(const unsigned short* t) {
    u32x4 v;
    v.x = (unsigned)t[0] | ((unsigned)t[1] << 16);
    v.y = (unsigned)t[2] | ((unsigned)t[3] << 16);
    v.z = (unsigned)t[4] | ((unsigned)t[5] << 16);
    v.w = (unsigned)t[6] | ((unsigned)t[7] << 16);
    return v;
}

DEV void edge_sd(int i, int E, const int* __restrict__ src, const int* __restrict__ dst,
                 int& s, int& d) {
    if (i < E) { s = src[i]; d = dst[i]; }
    else       { s = d = i - E; }  // self-loops appended as arange(N)
}

// detect helper: wave-level 256-sample scan of one array's low 16-bit halves
DEV int detect_wave(const void* p, int n, int lane) {
    const unsigned short* u16 = (const unsigned short*)p;
    bool insane = false;
#pragma unroll
    for (int r = 0; r < 4; ++r) {
        int idx = lane + r * 64;
        if (idx < n) {
            unsigned short u = u16[idx];
            unsigned e = (u >> 7) & 0xFFu;
            insane |= (e >= 0xC8u) || (e == 0u && (u & 0x7Fu) != 0u);
        }
    }
    return (__ballot(insane) != 0ull) ? 1 : 0;
}

#define G_BIN 128

// ---------------- K1: fused gemm1 (blocks [0,gb)) + binA hist ([gb,gb+G_BIN))
//                  + dtype detect (block gb+G_BIN) ----------------
__global__ __launch_bounds__(256) void k_fused1(
    // gemm1
    const void* __restrict__ x, const void* __restrict__ W,
    const void* __restrict__ a_s, const void* __restrict__ a_d,
    __hip_bfloat16* __restrict__ h, float* __restrict__ als, float* __restrict__ ald,
    int N, int gb, int nx, int nW1,
    // binA
    const int* __restrict__ src, const int* __restrict__ dst,
    int* __restrict__ hist, int E, int EA, int chunk,
    // detect (for downstream kernels)
    const void* a5, int n5, const void* a6, int n6, const void* a7, int n7,
    const void* a8, int n8, const void* a9, int n9,
    int* __restrict__ flags)
{
    const int tid = threadIdx.x;
    const int bid = blockIdx.x;

    if (bid >= gb) {
        if (bid == gb + G_BIN) {
            // global detect for downstream consumers (flags[0..8])
            const void* ps[9] = {x, W, a_s, a_d, a5, a6, a7, a8, a9};
            const int   ns[9] = {nx, nW1, 64, 64, n5, n6, n7, n8, n9};
            const int w = tid >> 6, lane = tid & 63;
            for (int k = w; k < 9; k += 4) {
                int f = detect_wave(ps[k], ns[k], lane);
                if (lane == 0) flags[k] = f;
            }
            return;
        }
        // ---- binA: coarse histogram ----
        __shared__ int cnt[256];
        cnt[tid] = 0;
        __syncthreads();
        const int cb = bid - gb;
        const int lo = cb * chunk;
        const int hi = min(lo + chunk, EA);
        for (int i = lo + tid; i < hi; i += 256) {
            int s, d; edge_sd(i, E, src, dst, s, d);
            atomicAdd(&cnt[d >> 8], 1);
        }
        __syncthreads();
        hist[cb * 256 + tid] = cnt[tid];
        return;
    }

    // ---- gemm1: h = x(N,128)@W1(128,64) + fused logits ----
    __shared__ __align__(16) unsigned short sMem[2 * 64 * 136];
    __shared__ float sAs[64], sAd[64];
    __shared__ int sFl[4];
    unsigned short* sA = sMem;
    unsigned short* sB = sMem + 64 * 136;
    float* sOut = (float*)sMem;

    {   // inline dtype detect: wave w checks array w
        const void* ps4[4] = {x, W, a_s, a_d};
        const int   ns4[4] = {nx, nW1, 64, 64};
        const int w = tid >> 6, lane = tid & 63;
        int f = detect_wave(ps4[w], ns4[w], lane);
        if (lane == 0) sFl[w] = f;
    }
    __syncthreads();
    const int fx = sFl[0], fw = sFl[1];

    const int row0 = bid * 64;
    if (tid < 64) sAs[tid] = loadF(a_s, tid, sFl[2]);
    else if (tid < 128) sAd[tid - 64] = loadF(a_d, tid - 64, sFl[3]);

    if (!fx) {
        const uint4* xg = (const uint4*)x;
#pragma unroll
        for (int it = 0; it < 2; ++it) {
            int g = tid + it * 256;
            int r = g >> 4, c16 = g & 15;
            uint4 v = (row0 + r < N) ? xg[(size_t)(row0 + r) * 16 + c16]
                                     : make_uint4(0, 0, 0, 0);
            *(uint4*)(sA + r * 136 + c16 * 8) = v;
        }
    } else {
        for (int i = tid; i < 64 * 128; i += 256) {
            int r = i >> 7, k = i & 127;
            float v = (row0 + r < N) ? ((const float*)x)[(size_t)(row0 + r) * 128 + k] : 0.f;
            sA[r * 136 + k] = f2bu(v);
        }
    }
    if (!fw) {
        const unsigned short* Wg = (const unsigned short*)W;
        const int n = tid & 63;
        int k0 = (tid >> 6) * 8;
#pragma unroll
        for (int rep = 0; rep < 4; ++rep, k0 += 32) {
            unsigned short t[8];
#pragma unroll
            for (int j = 0; j < 8; ++j) t[j] = Wg[(size_t)(k0 + j) * 64 + n];
            *(uint4*)(sB + n * 136 + k0) = pack8(t);
        }
    } else {
        const float* Wg = (const float*)W;
        for (int i = tid; i < 128 * 64; i += 256) {
            int k = i >> 6, n = i & 63;
            sB[n * 136 + k] = f2bu(Wg[i]);
        }
    }
    __syncthreads();

    const int w = tid >> 6, lane = tid & 63;
    const int m0 = w * 16;
    const int qr = lane >> 4;
    const int lc = lane & 15;

    bf16x8 afrag[4];
#pragma unroll
    for (int c = 0; c < 4; ++c) {
        U4 u; u.u = *(const uint4*)(sA + (m0 + lc) * 136 + c * 32 + qr * 8);
        afrag[c] = u.s;
    }
    f32x4 accs[4];
#pragma unroll
    for (int nt = 0; nt < 4; ++nt) {
        f32x4 acc = {0.f, 0.f, 0.f, 0.f};
#pragma unroll
        for (int c = 0; c < 4; ++c) {
            U4 u; u.u = *(const uint4*)(sB + (nt * 16 + lc) * 136 + c * 32 + qr * 8);
            acc = __builtin_amdgcn_mfma_f32_16x16x32_bf16(afrag[c], u.s, acc, 0, 0, 0);
        }
        accs[nt] = acc;
    }
    __syncthreads();

#pragma unroll
    for (int nt = 0; nt < 4; ++nt)
#pragma unroll
        for (int reg = 0; reg < 4; ++reg)
            sOut[(m0 + qr * 4 + reg) * 68 + nt * 16 + lc] = accs[nt][reg];
    __syncthreads();

    {
        const int r = tid >> 2, seg = tid & 3;
        const int row = row0 + r;
        const float* po = sOut + r * 68 + seg * 16;
        float ps = 0.f, pd = 0.f;
        unsigned short ob[16];
#pragma unroll
        for (int i = 0; i < 16; ++i) {
            float v = po[i];
            ps = fmaf(v, sAs[seg * 16 + i], ps);
            pd = fmaf(v, sAd[seg * 16 + i], pd);
            ob[i] = f2bu(v);
        }
        if (row < N) {
            uint4* hp = (uint4*)((unsigned short*)h + (size_t)row * 64 + seg * 16);
            hp[0] = pack8(ob);
            hp[1] = pack8(ob + 8);
        }
        ps += __shfl_xor(ps, 1, 64); ps += __shfl_xor(ps, 2, 64);
        pd += __shfl_xor(pd, 1, 64); pd += __shfl_xor(pd, 2, 64);
        if (seg == 0 && row < N) { als[row] = ps; ald[row] = pd; }
    }
}

// ---------------- binC2: fused scan + scatter ----------------
__global__ __launch_bounds__(256) void k_binC2(
    const int* __restrict__ src, const int* __restrict__ dst,
    const int* __restrict__ hist, int* __restrict__ btot,
    unsigned* __restrict__ ebuf, int E, int EA, int chunk)
{
    __shared__ int sm[256];
    __shared__ int cur[256];
    const int tid = threadIdx.x;
    const int cb = blockIdx.x;

    int tot = 0, mine = 0;
#pragma unroll 4
    for (int c = 0; c < G_BIN; ++c) {
        int v = hist[c * 256 + tid];     // coalesced across tid
        tot += v;
        if (c < cb) mine += v;
    }
    if (cb == 0) btot[tid] = tot;
    sm[tid] = tot;
    __syncthreads();
#pragma unroll
    for (int off = 1; off < 256; off <<= 1) {
        int t = (tid >= off) ? sm[tid - off] : 0;
        __syncthreads();
        sm[tid] += t;
        __syncthreads();
    }
    cur[tid] = (sm[tid] - tot) + mine;   // bucket start + my block's offset
    __syncthreads();
    const int lo = cb * chunk;
    const int hi = min(lo + chunk, EA);
    for (int i = lo + tid; i < hi; i += 256) {
        int s, d; edge_sd(i, E, src, dst, s, d);
        int pos = atomicAdd(&cur[d >> 8], 1);
        ebuf[pos] = ((unsigned)(d & 255) << 17) | (unsigned)s;
    }
}

// ---------------- binD: per-bucket node sort -> row_ptr + paired edge records ----------------
// Emits ecol[j] = {src, bits(als1[src])}: gather1's weight input becomes a
// STREAMING read (random als latency paid here, off the critical chain,
// hidden by binD's abundant MLP).
__global__ __launch_bounds__(256) void k_binD(
    const unsigned* __restrict__ ebuf, const int* __restrict__ btot,
    const float* __restrict__ als,
    int* __restrict__ row_ptr, int2* __restrict__ ecol, int N)
{
    __shared__ int sm[256];
    __shared__ int cnt[256];
    __shared__ int pfx[256];
    const int tid = threadIdx.x;
    const int b = blockIdx.x;
    {
        int v = btot[tid];
        sm[tid] = v;
        __syncthreads();
#pragma unroll
        for (int off = 1; off < 256; off <<= 1) {
            int t = (tid >= off) ? sm[tid - off] : 0;
            __syncthreads();
            sm[tid] += t;
            __syncthreads();
        }
    }
    const int lo = (b == 0) ? 0 : sm[b - 1];
    const int hi = sm[b];
    cnt[tid] = 0;
    __syncthreads();
    for (int i = lo + tid; i < hi; i += 256)
        atomicAdd(&cnt[ebuf[i] >> 17], 1);
    __syncthreads();
    const int c = cnt[tid];
    pfx[tid] = c;
    __syncthreads();
#pragma unroll
    for (int off = 1; off < 256; off <<= 1) {
        int t = (tid >= off) ? pfx[tid - off] : 0;
        __syncthreads();
        pfx[tid] += t;
        __syncthreads();
    }
    const int excl = pfx[tid] - c;
    const int d = b * 256 + tid;
    if (d <= N) row_ptr[d] = lo + excl;
    __syncthreads();
    cnt[tid] = lo + excl;              // reuse as absolute cursor
    __syncthreads();
    for (int i = lo + tid; i < hi; i += 256) {
        unsigned v = ebuf[i];
        const int s = (int)(v & 0x1FFFFu);
        int pos = atomicAdd(&cnt[v >> 17], 1);
        ecol[pos] = make_int2(s, __float_as_int(als[s]));
    }
}

// ---------------- MFMA layer-2 GEMM: h2 = relu(agg+b1)@W2(64,64), in-place ----------------
__global__ __launch_bounds__(256) void k_gemm2(
    __hip_bfloat16* __restrict__ agg, const void* __restrict__ b1,
    const void* __restrict__ W, const void* __restrict__ a_s,
    const void* __restrict__ a_d, const int* __restrict__ flags,
    float* __restrict__ als, float* __restrict__ ald, int N)
{
    __shared__ __align__(16) unsigned short sMem[2 * 64 * 72];
    __shared__ float sAs[64], sAd[64], sBias[64];
    unsigned short* sA = sMem;
    unsigned short* sB = sMem + 64 * 72;
    float* sOut = (float*)sMem;

    const int tid = threadIdx.x;
    const int row0 = blockIdx.x * 64;
    const int fw = flags[5];

    if (tid < 64) sAs[tid] = loadF(a_s, tid, flags[6]);
    else if (tid < 128) sAd[tid - 64] = loadF(a_d, tid - 64, flags[7]);
    else if (tid < 192) sBias[tid - 128] = loadF(b1, tid - 128, flags[4]);
    __syncthreads();

    {
        const uint4* ag = (const uint4*)agg;
#pragma unroll
        for (int it = 0; it < 2; ++it) {
            int g = tid + it * 256;
            int r = g >> 3, c8 = g & 7;
            uint4 v = (row0 + r < N) ? ag[(size_t)(row0 + r) * 8 + c8]
                                     : make_uint4(0, 0, 0, 0);
            unsigned short in[8] = {
                (unsigned short)(v.x & 0xFFFF), (unsigned short)(v.x >> 16),
                (unsigned short)(v.y & 0xFFFF), (unsigned short)(v.y >> 16),
                (unsigned short)(v.z & 0xFFFF), (unsigned short)(v.z >> 16),
                (unsigned short)(v.w & 0xFFFF), (unsigned short)(v.w >> 16)};
            unsigned short ob[8];
#pragma unroll
            for (int j = 0; j < 8; ++j) {
                float t = bu2f(in[j]) + sBias[c8 * 8 + j];
                ob[j] = f2bu(t > 0.f ? t : 0.f);
            }
            *(uint4*)(sA + r * 72 + c8 * 8) = pack8(ob);
        }
    }
    if (!fw) {
        const unsigned short* Wg = (const unsigned short*)W;
        const int n = tid & 63;
        int k0 = (tid >> 6) * 8;
#pragma unroll
        for (int rep = 0; rep < 2; ++rep, k0 += 32) {
            unsigned short t[8];
#pragma unroll
            for (int j = 0; j < 8; ++j) t[j] = Wg[(size_t)(k0 + j) * 64 + n];
            *(uint4*)(sB + n * 72 + k0) = pack8(t);
        }
    } else {
        const float* Wg = (const float*)W;
        for (int i = tid; i < 64 * 64; i += 256) {
            int k = i >> 6, n = i & 63;
            sB[n * 72 + k] = f2bu(Wg[i]);
        }
    }
    __syncthreads();

    const int w = tid >> 6, lane = tid & 63;
    const int m0 = w * 16;
    const int qr = lane >> 4, lc = lane & 15;

    bf16x8 afrag[2];
#pragma unroll
    for (int c = 0; c < 2; ++c) {
        U4 u; u.u = *(const uint4*)(sA + (m0 + lc) * 72 + c * 32 + qr * 8);
        afrag[c] = u.s;
    }
    f32x4 accs[4];
#pragma unroll
    for (int nt = 0; nt < 4; ++nt) {
        f32x4 acc = {0.f, 0.f, 0.f, 0.f};
#pragma unroll
        for (int c = 0; c < 2; ++c) {
            U4 u; u.u = *(const uint4*)(sB + (nt * 16 + lc) * 72 + c * 32 + qr * 8);
            acc = __builtin_amdgcn_mfma_f32_16x16x32_bf16(afrag[c], u.s, acc, 0, 0, 0);
        }
        accs[nt] = acc;
    }
    __syncthreads();
#pragma unroll
    for (int nt = 0; nt < 4; ++nt)
#pragma unroll
        for (int reg = 0; reg < 4; ++reg)
            sOut[(m0 + qr * 4 + reg) * 68 + nt * 16 + lc] = accs[nt][reg];
    __syncthreads();

    {
        const int r = tid >> 2, seg = tid & 3;
        const int row = row0 + r;
        const float* po = sOut + r * 68 + seg * 16;
        float ps = 0.f, pd = 0.f;
        unsigned short ob[16];
#pragma unroll
        for (int i = 0; i < 16; ++i) {
            float v = po[i];
            ps = fmaf(v, sAs[seg * 16 + i], ps);
            pd = fmaf(v, sAd[seg * 16 + i], pd);
            ob[i] = f2bu(v);
        }
        if (row < N) {
            uint4* hp = (uint4*)((unsigned short*)agg + (size_t)row * 64 + seg * 16);
            hp[0] = pack8(ob);
            hp[1] = pack8(ob + 8);
        }
        ps += __shfl_xor(ps, 1, 64); ps += __shfl_xor(ps, 2, 64);
        pd += __shfl_xor(pd, 1, 64); pd += __shfl_xor(pd, 2, 64);
        if (seg == 0 && row < N) { als[row] = ps; ald[row] = pd; }
    }
}

// ---------------- CSR gather (R0 eg/fg strided structure + streaming edge
// records + 1-ahead h prefetch) ----------------
// MODE 0 (layer 1): weight source = ecol[j].y (STREAMING, precomputed by binD)
//   -> only ONE random load level (h row), prefetched 1-ahead.
// MODE 1 (layer 2): weight source = als[ecol[j].x] (random, parallel to h2).
template<int MODE>
__global__ __launch_bounds__(256) void k_gather_t(
    const int* __restrict__ row_ptr, const int2* __restrict__ ecol,
    const float* __restrict__ als, const float* __restrict__ ald,
    const __hip_bfloat16* __restrict__ h,
    __hip_bfloat16* __restrict__ agg_out,
    void* __restrict__ final_out,
    const void* __restrict__ bias, const int* __restrict__ flags, int N)
{
    const int tid = threadIdx.x;
    const int lane = tid & 63;
    const int eg = lane >> 3, fg = lane & 7;
    const int wid = blockIdx.x * 4 + (tid >> 6);
    const int nw  = gridDim.x * 4;

    float bv[8]; int f0 = 0;
    if (MODE == 1) {
        f0 = flags[0];
#pragma unroll
        for (int k = 0; k < 8; ++k) bv[k] = loadF(bias, fg * 8 + k, flags[8]);
    }

    for (int d = wid; d < N; d += nw) {
        const float aldd = ald[d];
        const int beg = row_ptr[d], end = row_ptr[d + 1];
        float acc[8] = {0.f,0.f,0.f,0.f,0.f,0.f,0.f,0.f};
        float den = 0.f;
        int j = beg + eg;
        if (j < end) {
            int2 e = ecol[j];
            float aC = (MODE == 0) ? __int_as_float(e.y) : als[e.x];
            uint4 hvC = *reinterpret_cast<const uint4*>(h + (size_t)e.x * 64 + fg * 8);
            for (; j < end; j += 8) {
                const int jn = j + 8;
                int2 eN = make_int2(0, 0);
                float aN = 0.f;
                uint4 hvN = make_uint4(0, 0, 0, 0);
                if (jn < end) {                     // 1-ahead: record + h row
                    eN = ecol[jn];
                    aN = (MODE == 0) ? __int_as_float(eN.y) : als[eN.x];
                    hvN = *reinterpret_cast<const uint4*>(h + (size_t)eN.x * 64 + fg * 8);
                }
                const float w = __expf(lrelu(aC + aldd));
                den += w;
                acc[0] = fmaf(w, __uint_as_float(hvC.x << 16),          acc[0]);
                acc[1] = fmaf(w, __uint_as_float(hvC.x & 0xFFFF0000u),  acc[1]);
                acc[2] = fmaf(w, __uint_as_float(hvC.y << 16),          acc[2]);
                acc[3] = fmaf(w, __uint_as_float(hvC.y & 0xFFFF0000u),  acc[3]);
                acc[4] = fmaf(w, __uint_as_float(hvC.z << 16),          acc[4]);
                acc[5] = fmaf(w, __uint_as_float(hvC.z & 0xFFFF0000u),  acc[5]);
                acc[6] = fmaf(w, __uint_as_float(hvC.w << 16),          acc[6]);
                acc[7] = fmaf(w, __uint_as_float(hvC.w & 0xFFFF0000u),  acc[7]);
                e = eN; aC = aN; hvC = hvN;
            }
        }
#pragma unroll
        for (int off = 8; off <= 32; off <<= 1) {
            den += __shfl_xor(den, off, 64);
#pragma unroll
            for (int q = 0; q < 8; ++q) acc[q] += __shfl_xor(acc[q], off, 64);
        }
        if (eg == 0) {
            const float inv = 1.f / den;
            if (MODE == 1) {
                float vb[8];
#pragma unroll
                for (int q = 0; q < 8; ++q) vb[q] = fmaf(acc[q], inv, bv[q]);
                if (f0) {
                    float* o = (float*)final_out + (size_t)d * 64 + fg * 8;
                    f32x4 o0 = {vb[0], vb[1], vb[2], vb[3]};
                    f32x4 o1 = {vb[4], vb[5], vb[6], vb[7]};
                    __builtin_nontemporal_store(o0, (f32x4*)o);
                    __builtin_nontemporal_store(o1, (f32x4*)(o + 4));
                } else {
                    unsigned short ob[8];
#pragma unroll
                    for (int q = 0; q < 8; ++q) ob[q] = f2bu(vb[q]);
                    __builtin_nontemporal_store(pack8v(ob),
                        reinterpret_cast<u32x4*>((__hip_bfloat16*)final_out + (size_t)d * 64 + fg * 8));
                }
            } else {
                unsigned short ob[8];
#pragma unroll
                for (int q = 0; q < 8; ++q) ob[q] = f2bu(acc[q] * inv);
                __builtin_nontemporal_store(pack8v(ob),
                    reinterpret_cast<u32x4*>(agg_out + (size_t)d * 64 + fg * 8));
            }
        }
    }
}

extern "C" void kernel_launch(void* const* d_in, const int* in_sizes, int n_in,
                              void* d_out, int out_size, void* d_ws, size_t ws_size,
                              hipStream_t stream)
{
    const void* x   = d_in[0];
    const int*  ei  = (const int*)d_in[1];
    const void* W1  = d_in[2];
    const void* as1 = d_in[3];
    const void* ad1 = d_in[4];
    const void* b1  = d_in[5];
    const void* W2  = d_in[6];
    const void* as2 = d_in[7];
    const void* ad2 = d_in[8];
    const void* b2  = d_in[9];

    const int N  = in_sizes[0] / 128;   // 50000
    const int E  = in_sizes[1] / 2;     // 800000
    const int EA = E + N;
    const int* src = ei;
    const int* dst = ei + E;

    uintptr_t base = (uintptr_t)d_ws;
    auto alloc = [&](size_t bytes) { uintptr_t p = base; base += (bytes + 63) & ~(size_t)63; return p; };
    int*      flags    = (int*)alloc(64 * 4);
    float*    als      = (float*)alloc((size_t)N * 4);
    float*    ald      = (float*)alloc((size_t)N * 4);
    int*      row_ptr  = (int*)alloc((size_t)(N + 1) * 4);
    int*      hist     = (int*)alloc((size_t)G_BIN * 256 * 4);
    int*      btot     = (int*)alloc(256 * 4);
    unsigned* ebuf     = (unsigned*)alloc((size_t)EA * 4);
    int2*     ecol     = (int2*)alloc((size_t)EA * 8);
    __hip_bfloat16* hbuf   = (__hip_bfloat16*)alloc((size_t)N * 64 * 2);
    __hip_bfloat16* aggbuf = (__hip_bfloat16*)alloc((size_t)N * 64 * 2);

    const int gatherb = 2048;             // persistent: 8 blocks/CU resident
    const int gb  = (N + 63) / 64;        // gemm blocks: 64 rows/block
    const int NBK = (N + 255) / 256;      // dst buckets (<= 256)
    const int chunk = (EA + G_BIN - 1) / G_BIN;

    // ---- K1: gemm1 || binA || detect (all independent) ----
    k_fused1<<<gb + G_BIN + 1, 256, 0, stream>>>(
        x, W1, as1, ad1, hbuf, als, ald, N, gb, in_sizes[0], in_sizes[2],
        src, dst, hist, E, EA, chunk,
        b1, in_sizes[5], W2, in_sizes[6], as2, in_sizes[7], ad2, in_sizes[8],
        b2, in_sizes[9], flags);
    // ---- CSR finish ----
    k_binC2<<<G_BIN, 256, 0, stream>>>(src, dst, hist, btot, ebuf, E, EA, chunk);
    k_binD<<<NBK, 256, 0, stream>>>(ebuf, btot, als, row_ptr, ecol, N);

    // ---- layer 1 gather (streaming weights via ecol.y) ----
    k_gather_t<0><<<gatherb, 256, 0, stream>>>(row_ptr, ecol, nullptr, ald, hbuf,
                                               aggbuf, nullptr, nullptr, flags, N);
    // ---- layer 2 ----
    k_gemm2<<<gb, 256, 0, stream>>>(aggbuf, b1, W2, as2, ad2, flags, als, ald, N);
    k_gather_t<1><<<gatherb, 256, 0, stream>>>(row_ptr, ecol, als, ald, aggbuf,
                                               nullptr, d_out, b2, flags, N);
    (void)out_size; (void)ws_size; (void)n_in;
}